// Round 5
// baseline (2659.008 us; speedup 1.0000x reference)
//
#include <hip/hip_runtime.h>
#include <math.h>

// ---------------------------------------------------------------------------
// InfoNCE on MI355X — v5.
// T1[i,j] = tail(relu(hx[j]+hy[i]+b1)) = fused GEMM M=262144, N=512, K=512,
// A formed on the fly; bf16 hi/lo split (3 MFMA products, AlBl dropped).
// v5 vs v3 (v4's atomics/small-tile regressed; reverted):
//  - XOR-swizzled A in LDS (row stride 64 elems, slot p = s^(row&7)):
//    conflict-free staged writes AND fragment reads (v3: 2.1e7 conflict cyc).
//  - K-chunk 64 = two 32-k MFMA phases per barrier (8 barriers, was 16).
//  - Staging split in halves, loads/writes spread through the MFMA shadow;
//    B prefetched one 32-k step ahead; wave-staggered tm order.
//  - Raw scores stored (no softplus in hot kernel); reductions use
//    exp(softplus(z)) == 1+e^z. No atomics, no memset.
// ---------------------------------------------------------------------------

typedef __bf16 bf16x8 __attribute__((ext_vector_type(8)));
typedef float  f32x4  __attribute__((ext_vector_type(4)));

#define H    512
#define NPTS 512
#define XD   128

// ---------------- prep: hx, hy(+b1); W2 -> fragment-major bf16 hi/lo ------
__global__ __launch_bounds__(256) void prep_kernel(
    const float* __restrict__ x, const float* __restrict__ y,
    const float* __restrict__ W1x, const float* __restrict__ W1y,
    const float* __restrict__ b1, const float* __restrict__ W2,
    float* __restrict__ hx, float* __restrict__ hy,
    __bf16* __restrict__ w2h, __bf16* __restrict__ w2l) {
  __shared__ float xr[XD];
  const int b = blockIdx.x;
  const int t = threadIdx.x;
  if (b < 2 * NPTS) {
    const bool isY = (b >= NPTS);
    const int row = isY ? b - NPTS : b;
    const float* src = isY ? y : x;      // [NPTS][XD]
    const float* W   = isY ? W1y : W1x;  // [XD][H]
    if (t < XD) xr[t] = src[row * XD + t];
    __syncthreads();
    for (int c = t; c < H; c += 256) {
      float s = 0.f;
#pragma unroll
      for (int k = 0; k < XD; ++k) s = fmaf(xr[k], W[k * H + c], s);
      if (isY) hy[row * H + c] = s + b1[c];   // fold b1 into hy
      else     hx[row * H + c] = s;
    }
  } else {
    // W2[k][n] -> fragment-major: idx = ((n>>4)*16 + (k>>5))*512
    //                                   + (n&15)*32 + (k&31)
    // a wave's B-frag load (16 cols x 4 quads x 8 elems) = 1 KB contiguous.
    const int n = b - 2 * NPTS;
    for (int k = t; k < H; k += 256) {
      float v = W2[k * H + n];
      __bf16 hi = (__bf16)v;
      float lo = v - (float)hi;
      const int idx = (((n >> 4) * 16) + (k >> 5)) * 512 + (n & 15) * 32 + (k & 31);
      w2h[idx] = hi;
      w2l[idx] = (__bf16)lo;
    }
  }
}

// ---------------- pair GEMM + fused W3-reduce -> raw T1 -------------------
// grid 2048 = 32 i-groups x 64 j-groups; M-tile = 128 pairs (16 i x 8 j).
// 512 threads = 8 waves; wave w: all 128 rows x cols [w*64, w*64+64)
// (8 m-tiles x 4 n-tiles, acc[8][4]). K: 8 chunks of 64 (2 MFMA phases of
// 32 each), double-buffered swizzled LDS, ONE barrier per chunk.
__global__ __launch_bounds__(512, 2) void pair_kernel(
    const float* __restrict__ hx, const float* __restrict__ hy,
    const __bf16* __restrict__ w2h, const __bf16* __restrict__ w2l,
    const float* __restrict__ b2, const float* __restrict__ W3,
    float* __restrict__ T1raw) {
  // A chunk: 128 rows x 64 elems, row = 8 slots of 8 bf16 (16 B),
  // logical slot s stored at physical p = s ^ (row & 7)  -> conflict-free.
  __shared__ __align__(16) __bf16 Ah[2][128 * 64];
  __shared__ __align__(16) __bf16 Al[2][128 * 64];
  __shared__ float red[8][128];

  const int t    = threadIdx.x;
  const int i0   = (blockIdx.x >> 6) * 16;
  const int j0   = (blockIdx.x & 63) * 8;
  const int wave = t >> 6;
  const int lane = t & 63;
  const int col  = lane & 15;
  const int quad = lane >> 4;

  // staging: thread -> row sm (0..127), logical slots sb, sb+1 (8 elems each)
  const int sm = t >> 2;
  const int sb = (t & 3) * 2;
  const float* hxp = hx + (j0 + (sm & 7)) * H;   // tj = sm&7
  const float* hyp = hy + (i0 + (sm >> 3)) * H;  // ti = sm>>3

  const int boff = col * 32 + quad * 8;   // lane offset inside 1KB B-frag
  const int g0   = wave * 4;              // B n-group base (n>>4)

  f32x4 acc[8][4] = {};
  bf16x8 Bh[2][4], Bl[2][4];

  float4 sx0, sx1, sy0, sy1;   // one staging half in flight (16 regs)

  auto load_half = [&](int kc, int h) {
    const int k = kc * 64 + (sb + h) * 8;
    sx0 = *(const float4*)(hxp + k);
    sx1 = *(const float4*)(hxp + k + 4);
    sy0 = *(const float4*)(hyp + k);
    sy1 = *(const float4*)(hyp + k + 4);
  };
  auto write_half = [&](int buf, int h) {
    float a[8] = {sx0.x + sy0.x, sx0.y + sy0.y, sx0.z + sy0.z, sx0.w + sy0.w,
                  sx1.x + sy1.x, sx1.y + sy1.y, sx1.z + sy1.z, sx1.w + sy1.w};
    bf16x8 hv, lv;
#pragma unroll
    for (int e = 0; e < 8; ++e) {
      float v = a[e] > 0.f ? a[e] : 0.f;   // first relu
      __bf16 hi = (__bf16)v;
      hv[e] = hi;
      lv[e] = (__bf16)(v - (float)hi);
    }
    const int off = sm * 64 + ((sb + h) ^ (sm & 7)) * 8;
    *(bf16x8*)(&Ah[buf][off]) = hv;
    *(bf16x8*)(&Al[buf][off]) = lv;
  };
  auto load_B = [&](int g) {   // prefetch B frags for 32-k step g into slot g&1
#pragma unroll
    for (int tn = 0; tn < 4; ++tn) {
      const int base = (((g0 + tn) * 16) + g) * 512 + boff;
      Bh[g & 1][tn] = *(const bf16x8*)(w2h + base);
      Bl[g & 1][tn] = *(const bf16x8*)(w2l + base);
    }
  };
  auto mfma_phase = [&](int buf, int kh, int par) {
#pragma unroll
    for (int tt = 0; tt < 8; ++tt) {
      const int tm  = (tt + wave) & 7;             // stagger waves' LDS bursts
      const int row = tm * 16 + col;
      const int p   = (kh * 4 + quad) ^ (col & 7); // row&7 == col&7
      const int off = row * 64 + p * 8;
      bf16x8 Afh = *(const bf16x8*)(&Ah[buf][off]);
      bf16x8 Afl = *(const bf16x8*)(&Al[buf][off]);
#pragma unroll
      for (int tn = 0; tn < 4; ++tn) {
        acc[tm][tn] = __builtin_amdgcn_mfma_f32_16x16x32_bf16(Afh, Bh[par][tn], acc[tm][tn], 0, 0, 0);
        acc[tm][tn] = __builtin_amdgcn_mfma_f32_16x16x32_bf16(Afh, Bl[par][tn], acc[tm][tn], 0, 0, 0);
        acc[tm][tn] = __builtin_amdgcn_mfma_f32_16x16x32_bf16(Afl, Bh[par][tn], acc[tm][tn], 0, 0, 0);
      }
    }
  };

  // prologue: stage chunk 0 (both halves), load B for 32-k step 0
  load_half(0, 0); write_half(0, 0);
  load_half(0, 1); write_half(0, 1);
  load_B(0);
  __syncthreads();

#pragma unroll 2
  for (int kc = 0; kc < 8; ++kc) {
    const int cur = kc & 1, nxt = cur ^ 1;
    // ---- kh = 0 (32-k step g = 2*kc, B parity 0) ----
    if (kc < 7) load_half(kc + 1, 0);
    load_B(2 * kc + 1);                      // B for kh=1, parity 1
    mfma_phase(cur, 0, 0);
    if (kc < 7) write_half(nxt, 0);
    // ---- kh = 1 (32-k step g = 2*kc+1, B parity 1) ----
    if (kc < 7) {
      load_half(kc + 1, 1);
      load_B(2 * kc + 2);                    // B for next chunk kh=0, parity 0
    }
    mfma_phase(cur, 1, 1);
    if (kc < 7) write_half(nxt, 1);
    __syncthreads();
  }

  // epilogue: v = relu(h2 + b2); p = v*W3; reduce over 16 col-lanes;
  // store RAW score (softplus/b3 folded into reduction kernels).
  float bb[4], w3v[4];
#pragma unroll
  for (int tn = 0; tn < 4; ++tn) {
    const int n = wave * 64 + tn * 16 + col;
    bb[tn]  = b2[n];
    w3v[tn] = W3[n];
  }
#pragma unroll
  for (int tm = 0; tm < 8; ++tm) {
#pragma unroll
    for (int reg = 0; reg < 4; ++reg) {
      float p = 0.f;
#pragma unroll
      for (int tn = 0; tn < 4; ++tn) {
        float v = acc[tm][tn][reg] + bb[tn];
        v = v > 0.f ? v : 0.f;               // second relu
        p = fmaf(v, w3v[tn], p);
      }
      p += __shfl_xor(p, 1);
      p += __shfl_xor(p, 2);
      p += __shfl_xor(p, 4);
      p += __shfl_xor(p, 8);
      if (col == 0) red[wave][tm * 16 + quad * 4 + reg] = p;
    }
  }
  __syncthreads();
  if (t < 128) {
    float s = red[0][t] + red[1][t] + red[2][t] + red[3][t] +
              red[4][t] + red[5][t] + red[6][t] + red[7][t];
    const int ti = t >> 3, tj = t & 7;
    T1raw[(i0 + ti) * NPTS + (j0 + tj)] = s;   // row = i (hy), col = j (hx)
  }
}

// ---------------- parallel lse over softplus(raw + b3): one wave per row --
// exp(softplus(z)) == 1 + e^z exactly, so lse = log(512 + sum e^z).
__global__ __launch_bounds__(512) void rowlse_kernel(
    const float* __restrict__ T1raw, const float* __restrict__ b3,
    float* __restrict__ lse) {
  const int r    = blockIdx.x * 8 + (threadIdx.x >> 6);
  const int lane = threadIdx.x & 63;
  const float b3v = b3[0];
  const float* row = T1raw + r * NPTS;
  float se = 0.f;
#pragma unroll
  for (int q = 0; q < 8; ++q) se += expf(row[lane + q * 64] + b3v);
#pragma unroll
  for (int off = 1; off < 64; off <<= 1) se += __shfl_xor(se, off);
  if (lane == 0) lse[r] = logf(512.0f + se);
}

// ---------------- final: mean(softplus(diag+b3)) - (mean(lse) - log N) ----
__global__ __launch_bounds__(512) void final_kernel(
    const float* __restrict__ T1raw, const float* __restrict__ b3,
    const float* __restrict__ lse, float* __restrict__ out) {
  __shared__ float s1[8], s2[8];
  const int t = threadIdx.x, lane = t & 63, w = t >> 6;
  const float z = T1raw[t * NPTS + t] + b3[0];
  float a = z > 0.f ? z + log1pf(expf(-z)) : log1pf(expf(z));  // T0 = softplus
  float b = lse[t];
#pragma unroll
  for (int off = 1; off < 64; off <<= 1) {
    a += __shfl_xor(a, off);
    b += __shfl_xor(b, off);
  }
  if (lane == 0) { s1[w] = a; s2[w] = b; }
  __syncthreads();
  if (t == 0) {
    float sa = 0.f, sb = 0.f;
#pragma unroll
    for (int i = 0; i < 8; ++i) { sa += s1[i]; sb += s2[i]; }
    out[0] = sa / 512.0f - sb / 512.0f + logf(512.0f);
  }
}

// ---------------------------------------------------------------------------
extern "C" void kernel_launch(void* const* d_in, const int* in_sizes, int n_in,
                              void* d_out, int out_size, void* d_ws, size_t ws_size,
                              hipStream_t stream) {
  const float* x   = (const float*)d_in[0];
  const float* y   = (const float*)d_in[1];
  const float* W1x = (const float*)d_in[2];
  const float* W1y = (const float*)d_in[3];
  const float* b1  = (const float*)d_in[4];
  const float* W2  = (const float*)d_in[5];
  const float* b2  = (const float*)d_in[6];
  const float* W3  = (const float*)d_in[7];
  const float* b3  = (const float*)d_in[8];

  float* ws = (float*)d_ws;
  float* hx = ws;                         // 512*512 f32
  float* hy = ws + 262144;                // 512*512 f32
  float* T1 = ws + 524288;                // 512*512 f32 (raw, pre-b3/softplus)
  __bf16* w2h = (__bf16*)(ws + 786432);   // 512*512 bf16 (fragment-major)
  __bf16* w2l = w2h + 262144;             // 512*512 bf16
  float* lse = ws + 786432 + 131072;      // 512 f32
  float* out = (float*)d_out;

  hipLaunchKernelGGL(prep_kernel, dim3(1536), dim3(256), 0, stream,
                     x, y, W1x, W1y, b1, W2, hx, hy, w2h, w2l);
  hipLaunchKernelGGL(pair_kernel, dim3(2048), dim3(512), 0, stream,
                     hx, hy, w2h, w2l, b2, W3, T1);
  hipLaunchKernelGGL(rowlse_kernel, dim3(64), dim3(512), 0, stream, T1, b3, lse);
  hipLaunchKernelGGL(final_kernel, dim3(1), dim3(512), 0, stream, T1, b3, lse, out);
}

// Round 6
// 617.409 us; speedup vs baseline: 4.3067x; 4.3067x over previous
//
#include <hip/hip_runtime.h>
#include <math.h>

// ---------------------------------------------------------------------------
// InfoNCE on MI355X — v6.
// T1[i,j] = tail(relu(hx[j]+hy[i]+b1)) = fused GEMM M=262144, N=512, K=512,
// A formed on the fly; bf16 hi/lo split (3 MFMA products, AlBl dropped).
// v6 = v5 with STATIC accumulator indexing (v5's tm=(tt+wave)&7 made
// acc[][] dynamically indexed -> demoted to scratch -> 8.9 GB spill traffic).
// Keeps: XOR-swizzled conflict-free LDS (verified: conflicts = 0),
// K-chunk 64 (8 barriers), half-staged loads in the MFMA shadow,
// cross-barrier B prefetch, raw-score epilogue (softplus folded into
// reductions via exp(softplus(z)) == 1+e^z).
// ---------------------------------------------------------------------------

typedef __bf16 bf16x8 __attribute__((ext_vector_type(8)));
typedef float  f32x4  __attribute__((ext_vector_type(4)));

#define H    512
#define NPTS 512
#define XD   128

// ---------------- prep: hx, hy(+b1); W2 -> fragment-major bf16 hi/lo ------
__global__ __launch_bounds__(256) void prep_kernel(
    const float* __restrict__ x, const float* __restrict__ y,
    const float* __restrict__ W1x, const float* __restrict__ W1y,
    const float* __restrict__ b1, const float* __restrict__ W2,
    float* __restrict__ hx, float* __restrict__ hy,
    __bf16* __restrict__ w2h, __bf16* __restrict__ w2l) {
  __shared__ float xr[XD];
  const int b = blockIdx.x;
  const int t = threadIdx.x;
  if (b < 2 * NPTS) {
    const bool isY = (b >= NPTS);
    const int row = isY ? b - NPTS : b;
    const float* src = isY ? y : x;      // [NPTS][XD]
    const float* W   = isY ? W1y : W1x;  // [XD][H]
    if (t < XD) xr[t] = src[row * XD + t];
    __syncthreads();
    for (int c = t; c < H; c += 256) {
      float s = 0.f;
#pragma unroll
      for (int k = 0; k < XD; ++k) s = fmaf(xr[k], W[k * H + c], s);
      if (isY) hy[row * H + c] = s + b1[c];   // fold b1 into hy
      else     hx[row * H + c] = s;
    }
  } else {
    // W2[k][n] -> fragment-major: idx = ((n>>4)*16 + (k>>5))*512
    //                                   + (n&15)*32 + (k&31)
    // a wave's B-frag load (16 cols x 4 quads x 8 elems) = 1 KB contiguous.
    const int n = b - 2 * NPTS;
    for (int k = t; k < H; k += 256) {
      float v = W2[k * H + n];
      __bf16 hi = (__bf16)v;
      float lo = v - (float)hi;
      const int idx = (((n >> 4) * 16) + (k >> 5)) * 512 + (n & 15) * 32 + (k & 31);
      w2h[idx] = hi;
      w2l[idx] = (__bf16)lo;
    }
  }
}

// ---------------- pair GEMM + fused W3-reduce -> raw T1 -------------------
// grid 2048 = 32 i-groups x 64 j-groups; M-tile = 128 pairs (16 i x 8 j).
// 512 threads = 8 waves; wave w: all 128 rows x cols [w*64, w*64+64)
// (8 m-tiles x 4 n-tiles, acc[8][4], STATIC indexing only). K: 8 chunks of
// 64 (2 MFMA phases of 32), double-buffered swizzled LDS, ONE barrier/chunk.
__global__ __launch_bounds__(512, 2) void pair_kernel(
    const float* __restrict__ hx, const float* __restrict__ hy,
    const __bf16* __restrict__ w2h, const __bf16* __restrict__ w2l,
    const float* __restrict__ b2, const float* __restrict__ W3,
    float* __restrict__ T1raw) {
  // A chunk: 128 rows x 64 elems, row = 8 slots of 8 bf16 (16 B),
  // logical slot s stored at physical p = s ^ (row & 7)  -> conflict-free.
  __shared__ __align__(16) __bf16 Ah[2][128 * 64];
  __shared__ __align__(16) __bf16 Al[2][128 * 64];
  __shared__ float red[8][128];

  const int t    = threadIdx.x;
  const int i0   = (blockIdx.x >> 6) * 16;
  const int j0   = (blockIdx.x & 63) * 8;
  const int wave = t >> 6;
  const int lane = t & 63;
  const int col  = lane & 15;
  const int quad = lane >> 4;

  // staging: thread -> row sm (0..127), logical slots sb, sb+1 (8 elems each)
  const int sm = t >> 2;
  const int sb = (t & 3) * 2;
  const float* hxp = hx + (j0 + (sm & 7)) * H;   // tj = sm&7
  const float* hyp = hy + (i0 + (sm >> 3)) * H;  // ti = sm>>3

  const int boff = col * 32 + quad * 8;   // lane offset inside 1KB B-frag
  const int g0   = wave * 4;              // B n-group base (n>>4)

  f32x4 acc[8][4] = {};
  bf16x8 Bh[2][4], Bl[2][4];

  float4 sx0, sx1, sy0, sy1;   // one staging half in flight (16 regs)

  auto load_half = [&](int kc, int h) {
    const int k = kc * 64 + (sb + h) * 8;
    sx0 = *(const float4*)(hxp + k);
    sx1 = *(const float4*)(hxp + k + 4);
    sy0 = *(const float4*)(hyp + k);
    sy1 = *(const float4*)(hyp + k + 4);
  };
  auto write_half = [&](int buf, int h) {
    float a[8] = {sx0.x + sy0.x, sx0.y + sy0.y, sx0.z + sy0.z, sx0.w + sy0.w,
                  sx1.x + sy1.x, sx1.y + sy1.y, sx1.z + sy1.z, sx1.w + sy1.w};
    bf16x8 hv, lv;
#pragma unroll
    for (int e = 0; e < 8; ++e) {
      float v = a[e] > 0.f ? a[e] : 0.f;   // first relu
      __bf16 hi = (__bf16)v;
      hv[e] = hi;
      lv[e] = (__bf16)(v - (float)hi);
    }
    const int off = sm * 64 + ((sb + h) ^ (sm & 7)) * 8;
    *(bf16x8*)(&Ah[buf][off]) = hv;
    *(bf16x8*)(&Al[buf][off]) = lv;
  };
  auto load_B = [&](int g, int par) {  // prefetch B frags for 32-k step g
#pragma unroll
    for (int tn = 0; tn < 4; ++tn) {
      const int base = (((g0 + tn) * 16) + g) * 512 + boff;
      Bh[par][tn] = *(const bf16x8*)(w2h + base);
      Bl[par][tn] = *(const bf16x8*)(w2l + base);
    }
  };
  auto mfma_phase = [&](int buf, int kh, int par) {
#pragma unroll
    for (int tm = 0; tm < 8; ++tm) {           // STATIC order (v5 lesson)
      const int row = tm * 16 + col;
      const int p   = (kh * 4 + quad) ^ (col & 7); // row&7 == col&7
      const int off = row * 64 + p * 8;
      bf16x8 Afh = *(const bf16x8*)(&Ah[buf][off]);
      bf16x8 Afl = *(const bf16x8*)(&Al[buf][off]);
#pragma unroll
      for (int tn = 0; tn < 4; ++tn) {
        acc[tm][tn] = __builtin_amdgcn_mfma_f32_16x16x32_bf16(Afh, Bh[par][tn], acc[tm][tn], 0, 0, 0);
        acc[tm][tn] = __builtin_amdgcn_mfma_f32_16x16x32_bf16(Afh, Bl[par][tn], acc[tm][tn], 0, 0, 0);
        acc[tm][tn] = __builtin_amdgcn_mfma_f32_16x16x32_bf16(Afl, Bh[par][tn], acc[tm][tn], 0, 0, 0);
      }
    }
  };

  // prologue: stage chunk 0 (both halves), load B for 32-k step 0
  load_half(0, 0); write_half(0, 0);
  load_half(0, 1); write_half(0, 1);
  load_B(0, 0);
  __syncthreads();

#pragma unroll 2
  for (int kc = 0; kc < 8; ++kc) {
    const int cur = kc & 1, nxt = cur ^ 1;
    // ---- kh = 0 (32-k step 2*kc, B parity 0) ----
    if (kc < 7) load_half(kc + 1, 0);
    load_B(2 * kc + 1, 1);                   // B for kh=1
    mfma_phase(cur, 0, 0);
    if (kc < 7) write_half(nxt, 0);
    // ---- kh = 1 (32-k step 2*kc+1, B parity 1) ----
    if (kc < 7) {
      load_half(kc + 1, 1);
      load_B(2 * kc + 2, 0);                 // B for next chunk's kh=0
    }
    mfma_phase(cur, 1, 1);
    if (kc < 7) write_half(nxt, 1);
    __syncthreads();
  }

  // epilogue: v = relu(h2 + b2); p = v*W3; reduce over 16 col-lanes;
  // store RAW score (softplus/b3 folded into reduction kernels).
  float bb[4], w3v[4];
#pragma unroll
  for (int tn = 0; tn < 4; ++tn) {
    const int n = wave * 64 + tn * 16 + col;
    bb[tn]  = b2[n];
    w3v[tn] = W3[n];
  }
#pragma unroll
  for (int tm = 0; tm < 8; ++tm) {
#pragma unroll
    for (int reg = 0; reg < 4; ++reg) {
      float p = 0.f;
#pragma unroll
      for (int tn = 0; tn < 4; ++tn) {
        float v = acc[tm][tn][reg] + bb[tn];
        v = v > 0.f ? v : 0.f;               // second relu
        p = fmaf(v, w3v[tn], p);
      }
      p += __shfl_xor(p, 1);
      p += __shfl_xor(p, 2);
      p += __shfl_xor(p, 4);
      p += __shfl_xor(p, 8);
      if (col == 0) red[wave][tm * 16 + quad * 4 + reg] = p;
    }
  }
  __syncthreads();
  if (t < 128) {
    float s = red[0][t] + red[1][t] + red[2][t] + red[3][t] +
              red[4][t] + red[5][t] + red[6][t] + red[7][t];
    const int ti = t >> 3, tj = t & 7;
    T1raw[(i0 + ti) * NPTS + (j0 + tj)] = s;   // row = i (hy), col = j (hx)
  }
}

// ---------------- parallel lse over softplus(raw + b3): one wave per row --
// exp(softplus(z)) == 1 + e^z exactly, so lse = log(512 + sum e^z).
__global__ __launch_bounds__(512) void rowlse_kernel(
    const float* __restrict__ T1raw, const float* __restrict__ b3,
    float* __restrict__ lse) {
  const int r    = blockIdx.x * 8 + (threadIdx.x >> 6);
  const int lane = threadIdx.x & 63;
  const float b3v = b3[0];
  const float* row = T1raw + r * NPTS;
  float se = 0.f;
#pragma unroll
  for (int q = 0; q < 8; ++q) se += expf(row[lane + q * 64] + b3v);
#pragma unroll
  for (int off = 1; off < 64; off <<= 1) se += __shfl_xor(se, off);
  if (lane == 0) lse[r] = logf(512.0f + se);
}

// ---------------- final: mean(softplus(diag+b3)) - (mean(lse) - log N) ----
__global__ __launch_bounds__(512) void final_kernel(
    const float* __restrict__ T1raw, const float* __restrict__ b3,
    const float* __restrict__ lse, float* __restrict__ out) {
  __shared__ float s1[8], s2[8];
  const int t = threadIdx.x, lane = t & 63, w = t >> 6;
  const float z = T1raw[t * NPTS + t] + b3[0];
  float a = z > 0.f ? z + log1pf(expf(-z)) : log1pf(expf(z));  // T0 = softplus
  float b = lse[t];
#pragma unroll
  for (int off = 1; off < 64; off <<= 1) {
    a += __shfl_xor(a, off);
    b += __shfl_xor(b, off);
  }
  if (lane == 0) { s1[w] = a; s2[w] = b; }
  __syncthreads();
  if (t == 0) {
    float sa = 0.f, sb = 0.f;
#pragma unroll
    for (int i = 0; i < 8; ++i) { sa += s1[i]; sb += s2[i]; }
    out[0] = sa / 512.0f - sb / 512.0f + logf(512.0f);
  }
}

// ---------------------------------------------------------------------------
extern "C" void kernel_launch(void* const* d_in, const int* in_sizes, int n_in,
                              void* d_out, int out_size, void* d_ws, size_t ws_size,
                              hipStream_t stream) {
  const float* x   = (const float*)d_in[0];
  const float* y   = (const float*)d_in[1];
  const float* W1x = (const float*)d_in[2];
  const float* W1y = (const float*)d_in[3];
  const float* b1  = (const float*)d_in[4];
  const float* W2  = (const float*)d_in[5];
  const float* b2  = (const float*)d_in[6];
  const float* W3  = (const float*)d_in[7];
  const float* b3  = (const float*)d_in[8];

  float* ws = (float*)d_ws;
  float* hx = ws;                         // 512*512 f32
  float* hy = ws + 262144;                // 512*512 f32
  float* T1 = ws + 524288;                // 512*512 f32 (raw, pre-b3/softplus)
  __bf16* w2h = (__bf16*)(ws + 786432);   // 512*512 bf16 (fragment-major)
  __bf16* w2l = w2h + 262144;             // 512*512 bf16
  float* lse = ws + 786432 + 131072;      // 512 f32
  float* out = (float*)d_out;

  hipLaunchKernelGGL(prep_kernel, dim3(1536), dim3(256), 0, stream,
                     x, y, W1x, W1y, b1, W2, hx, hy, w2h, w2l);
  hipLaunchKernelGGL(pair_kernel, dim3(2048), dim3(512), 0, stream,
                     hx, hy, w2h, w2l, b2, W3, T1);
  hipLaunchKernelGGL(rowlse_kernel, dim3(64), dim3(512), 0, stream, T1, b3, lse);
  hipLaunchKernelGGL(final_kernel, dim3(1), dim3(512), 0, stream, T1, b3, lse, out);
}

// Round 8
// 531.016 us; speedup vs baseline: 5.0074x; 1.1627x over previous
//
#include <hip/hip_runtime.h>
#include <math.h>

// ---------------------------------------------------------------------------
// InfoNCE on MI355X — v8.
// T1[i,j] = tail(relu(hx[j]+hy[i]+b1)) = fused GEMM M=262144, N=512, K=512,
// A formed on the fly; bf16 hi/lo split (3 MFMA products, AlBl dropped).
// v8 = v7 with the WORKSPACE COLLISION fixed: v7 placed rowsum at float
// offset 655360, overlapping w2l (bytes 2621440..3145728) -> the epilogue's
// atomicAdds corrupted B-lo while blocks read it -> NaN. rowsum now at
// 786432 (= 524288 + 262144 float-equivalents of the two bf16 arrays).
// Kernel logic unchanged from v7: 64-k chunks (8 barriers), whole-chunk
// staging post-barrier (32 regs), both B parities up-front (64 regs, no
// cross-chunk B prefetch), no K-loop unroll, XOR-swizzled conflict-free LDS,
// fused row-lse partials via atomicAdd (exp(softplus(z)) == 1+e^z).
// ---------------------------------------------------------------------------

typedef __bf16 bf16x8 __attribute__((ext_vector_type(8)));
typedef float  f32x4  __attribute__((ext_vector_type(4)));

#define H    512
#define NPTS 512
#define XD   128

// ---------------- prep: hx, hy(+b1); W2 -> fragment-major bf16 hi/lo ------
__global__ __launch_bounds__(256) void prep_kernel(
    const float* __restrict__ x, const float* __restrict__ y,
    const float* __restrict__ W1x, const float* __restrict__ W1y,
    const float* __restrict__ b1, const float* __restrict__ W2,
    float* __restrict__ hx, float* __restrict__ hy,
    __bf16* __restrict__ w2h, __bf16* __restrict__ w2l) {
  __shared__ float xr[XD];
  const int b = blockIdx.x;
  const int t = threadIdx.x;
  if (b < 2 * NPTS) {
    const bool isY = (b >= NPTS);
    const int row = isY ? b - NPTS : b;
    const float* src = isY ? y : x;      // [NPTS][XD]
    const float* W   = isY ? W1y : W1x;  // [XD][H]
    if (t < XD) xr[t] = src[row * XD + t];
    __syncthreads();
    for (int c = t; c < H; c += 256) {
      float s = 0.f;
#pragma unroll
      for (int k = 0; k < XD; ++k) s = fmaf(xr[k], W[k * H + c], s);
      if (isY) hy[row * H + c] = s + b1[c];   // fold b1 into hy
      else     hx[row * H + c] = s;
    }
  } else {
    // W2[k][n] -> fragment-major: idx = ((n>>4)*16 + (k>>5))*512
    //                                   + (n&15)*32 + (k&31)
    // a wave's B-frag load (16 cols x 4 quads x 8 elems) = 1 KB contiguous.
    const int n = b - 2 * NPTS;
    for (int k = t; k < H; k += 256) {
      float v = W2[k * H + n];
      __bf16 hi = (__bf16)v;
      float lo = v - (float)hi;
      const int idx = (((n >> 4) * 16) + (k >> 5)) * 512 + (n & 15) * 32 + (k & 31);
      w2h[idx] = hi;
      w2l[idx] = (__bf16)lo;
    }
  }
}

// ---------------- pair GEMM + fused tail + fused row-lse partials ---------
// grid 2048 = 32 i-groups x 64 j-groups; M-tile = 128 pairs (16 i x 8 j).
// 512 threads = 8 waves; wave w: all 128 rows x cols [w*64, w*64+64)
// (8 m-tiles x 4 n-tiles, acc[8][4] static-indexed). K: 8 chunks of 64
// (2 MFMA phases of 32), double-buffered swizzled LDS, ONE barrier/chunk.
__global__ __launch_bounds__(512, 2) void pair_kernel(
    const float* __restrict__ hx, const float* __restrict__ hy,
    const __bf16* __restrict__ w2h, const __bf16* __restrict__ w2l,
    const float* __restrict__ b2, const float* __restrict__ W3,
    const float* __restrict__ b3,
    float* __restrict__ rowsum, float* __restrict__ dsum) {
  // A chunk: 128 rows x 64 elems, row = 8 slots of 8 bf16 (16 B),
  // logical slot s stored at physical p = s ^ (row & 7)  -> conflict-free.
  __shared__ __align__(16) __bf16 Ah[2][128 * 64];
  __shared__ __align__(16) __bf16 Al[2][128 * 64];
  __shared__ float red[8][128];

  const int t    = threadIdx.x;
  const int i0   = (blockIdx.x >> 6) * 16;
  const int j0   = (blockIdx.x & 63) * 8;
  const int wave = t >> 6;
  const int lane = t & 63;
  const int col  = lane & 15;
  const int quad = lane >> 4;

  // staging: thread -> row sm (0..127), logical slots sb, sb+1 (8 elems each)
  const int sm = t >> 2;
  const int sb = (t & 3) * 2;
  const float* hxp = hx + (j0 + (sm & 7)) * H + sb * 8;   // tj = sm&7
  const float* hyp = hy + (i0 + (sm >> 3)) * H + sb * 8;  // ti = sm>>3
  const int aw0 = sm * 64 + ((sb    ) ^ (sm & 7)) * 8;
  const int aw1 = sm * 64 + ((sb + 1) ^ (sm & 7)) * 8;

  const int boff = col * 32 + quad * 8;   // lane offset inside 1KB B-frag
  const int g0   = wave * 4;              // B n-group base (n>>4)

  f32x4 acc[8][4] = {};
  float4 X0, X1, X2, X3, Y0, Y1, Y2, Y3;  // one chunk's staging (32 regs)

#define LOAD_STAGE(kc)                                              \
  {                                                                 \
    const float* px = hxp + (kc) * 64;                              \
    const float* py = hyp + (kc) * 64;                              \
    X0 = *(const float4*)(px);     X1 = *(const float4*)(px + 4);   \
    X2 = *(const float4*)(px + 8); X3 = *(const float4*)(px + 12);  \
    Y0 = *(const float4*)(py);     Y1 = *(const float4*)(py + 4);   \
    Y2 = *(const float4*)(py + 8); Y3 = *(const float4*)(py + 12);  \
  }

#define WRITE_STAGE(buf)                                                   \
  {                                                                        \
    float a0[8] = {X0.x + Y0.x, X0.y + Y0.y, X0.z + Y0.z, X0.w + Y0.w,     \
                   X1.x + Y1.x, X1.y + Y1.y, X1.z + Y1.z, X1.w + Y1.w};    \
    float a1[8] = {X2.x + Y2.x, X2.y + Y2.y, X2.z + Y2.z, X2.w + Y2.w,     \
                   X3.x + Y3.x, X3.y + Y3.y, X3.z + Y3.z, X3.w + Y3.w};    \
    bf16x8 hv0, lv0, hv1, lv1;                                             \
    _Pragma("unroll") for (int e = 0; e < 8; ++e) {                        \
      float v0 = a0[e] > 0.f ? a0[e] : 0.f;                                \
      float v1 = a1[e] > 0.f ? a1[e] : 0.f;                                \
      __bf16 h0 = (__bf16)v0, h1 = (__bf16)v1;                             \
      hv0[e] = h0; lv0[e] = (__bf16)(v0 - (float)h0);                      \
      hv1[e] = h1; lv1[e] = (__bf16)(v1 - (float)h1);                      \
    }                                                                      \
    *(bf16x8*)(&Ah[buf][aw0]) = hv0; *(bf16x8*)(&Al[buf][aw0]) = lv0;      \
    *(bf16x8*)(&Ah[buf][aw1]) = hv1; *(bf16x8*)(&Al[buf][aw1]) = lv1;      \
  }

#define LOAD_B(g, BH, BL)                                        \
  _Pragma("unroll") for (int tn = 0; tn < 4; ++tn) {             \
    const int base = (((g0 + tn) * 16) + (g)) * 512 + boff;      \
    BH[tn] = *(const bf16x8*)(w2h + base);                       \
    BL[tn] = *(const bf16x8*)(w2l + base);                       \
  }

#define MFMA_PHASE(buf, kh, BH, BL)                                            \
  _Pragma("unroll") for (int tm = 0; tm < 8; ++tm) {                           \
    const int row = tm * 16 + col;                                             \
    const int p   = ((kh) * 4 + quad) ^ (col & 7);                             \
    const int off = row * 64 + p * 8;                                          \
    bf16x8 Afh = *(const bf16x8*)(&Ah[buf][off]);                              \
    bf16x8 Afl = *(const bf16x8*)(&Al[buf][off]);                              \
    _Pragma("unroll") for (int tn = 0; tn < 4; ++tn) {                         \
      acc[tm][tn] = __builtin_amdgcn_mfma_f32_16x16x32_bf16(Afh, BH[tn], acc[tm][tn], 0, 0, 0); \
      acc[tm][tn] = __builtin_amdgcn_mfma_f32_16x16x32_bf16(Afh, BL[tn], acc[tm][tn], 0, 0, 0); \
      acc[tm][tn] = __builtin_amdgcn_mfma_f32_16x16x32_bf16(Afl, BH[tn], acc[tm][tn], 0, 0, 0); \
    }                                                                          \
  }

  // prologue: stage chunk 0
  LOAD_STAGE(0);
  WRITE_STAGE(0);
  __syncthreads();

#pragma unroll 1
  for (int kc = 0; kc < 8; ++kc) {
    const int cur = kc & 1, nxt = cur ^ 1;
    if (kc < 7) LOAD_STAGE(kc + 1);            // in flight across MFMA phases
    bf16x8 Bh0[4], Bl0[4], Bh1[4], Bl1[4];
    LOAD_B(2 * kc,     Bh0, Bl0);
    LOAD_B(2 * kc + 1, Bh1, Bl1);
    MFMA_PHASE(cur, 0, Bh0, Bl0);
    MFMA_PHASE(cur, 1, Bh1, Bl1);
    if (kc < 7) WRITE_STAGE(nxt);
    __syncthreads();
  }

  // epilogue: v = relu(h2 + b2); p = v*W3; reduce over 16 col-lanes
  float bb[4], w3v[4];
#pragma unroll
  for (int tn = 0; tn < 4; ++tn) {
    const int n = wave * 64 + tn * 16 + col;
    bb[tn]  = b2[n];
    w3v[tn] = W3[n];
  }
#pragma unroll
  for (int tm = 0; tm < 8; ++tm) {
#pragma unroll
    for (int reg = 0; reg < 4; ++reg) {
      float p = 0.f;
#pragma unroll
      for (int tn = 0; tn < 4; ++tn) {
        float v = acc[tm][tn][reg] + bb[tn];
        v = v > 0.f ? v : 0.f;               // second relu
        p = fmaf(v, w3v[tn], p);
      }
      p += __shfl_xor(p, 1);
      p += __shfl_xor(p, 2);
      p += __shfl_xor(p, 4);
      p += __shfl_xor(p, 8);
      if (col == 0) red[wave][tm * 16 + quad * 4 + reg] = p;
    }
  }
  __syncthreads();
  // fused row-lse partials: exp(softplus(z)) == 1 + e^z, so each row's
  // lse needs sum_j e^{z_ij}; this block contributes its 8 j's for 16 i's.
  if (t < 128) {
    float s = red[0][t] + red[1][t] + red[2][t] + red[3][t] +
              red[4][t] + red[5][t] + red[6][t] + red[7][t];
    const int ti = t >> 3, tj = t & 7;
    const float z = s + b3[0];
    float esum = expf(z);
    esum += __shfl_xor(esum, 1);
    esum += __shfl_xor(esum, 2);
    esum += __shfl_xor(esum, 4);
    if (tj == 0) atomicAdd(&rowsum[i0 + ti], esum);
    if (i0 + ti == j0 + tj) {                   // diag: T0 = softplus(z)
      const float sp = z > 0.f ? z + log1pf(expf(-z)) : log1pf(expf(z));
      atomicAdd(dsum, sp);
    }
  }
#undef LOAD_STAGE
#undef WRITE_STAGE
#undef LOAD_B
#undef MFMA_PHASE
}

// ---------------- final: mean(softplus(diag)) - (mean(lse) - log N) -------
// lse_i = log(512 + rowsum_i)
__global__ __launch_bounds__(512) void final_kernel(
    const float* __restrict__ rowsum, const float* __restrict__ dsum,
    float* __restrict__ out) {
  __shared__ float s2[8];
  const int t = threadIdx.x, lane = t & 63, w = t >> 6;
  float b = logf(512.0f + rowsum[t]);
#pragma unroll
  for (int off = 1; off < 64; off <<= 1) b += __shfl_xor(b, off);
  if (lane == 0) s2[w] = b;
  __syncthreads();
  if (t == 0) {
    float sb = 0.f;
#pragma unroll
    for (int i = 0; i < 8; ++i) sb += s2[i];
    out[0] = dsum[0] / 512.0f - sb / 512.0f + logf(512.0f);
  }
}

// ---------------------------------------------------------------------------
extern "C" void kernel_launch(void* const* d_in, const int* in_sizes, int n_in,
                              void* d_out, int out_size, void* d_ws, size_t ws_size,
                              hipStream_t stream) {
  const float* x   = (const float*)d_in[0];
  const float* y   = (const float*)d_in[1];
  const float* W1x = (const float*)d_in[2];
  const float* W1y = (const float*)d_in[3];
  const float* b1  = (const float*)d_in[4];
  const float* W2  = (const float*)d_in[5];
  const float* b2  = (const float*)d_in[6];
  const float* W3  = (const float*)d_in[7];
  const float* b3  = (const float*)d_in[8];

  float* ws = (float*)d_ws;
  float* hx = ws;                         // 512*512 f32  (floats 0..262143)
  float* hy = ws + 262144;                // 512*512 f32  (262144..524287)
  __bf16* w2h = (__bf16*)(ws + 524288);   // 512*512 bf16 (float-equiv 524288..655359)
  __bf16* w2l = w2h + 262144;             // 512*512 bf16 (float-equiv 655360..786431)
  float* rowsum = ws + 786432;            // 512 f32 — AFTER w2l (v7 bug fixed)
  float* dsum   = rowsum + 512;           // 1 f32
  float* out = (float*)d_out;

  hipLaunchKernelGGL(prep_kernel, dim3(1536), dim3(256), 0, stream,
                     x, y, W1x, W1y, b1, W2, hx, hy, w2h, w2l);
  hipMemsetAsync(rowsum, 0, 513 * sizeof(float), stream);
  hipLaunchKernelGGL(pair_kernel, dim3(2048), dim3(512), 0, stream,
                     hx, hy, w2h, w2l, b2, W3, b3, rowsum, dsum);
  hipLaunchKernelGGL(final_kernel, dim3(1), dim3(512), 0, stream,
                     rowsum, dsum, out);
}